// Round 2
// baseline (572.321 us; speedup 1.0000x reference)
//
#include <hip/hip_runtime.h>
#include <math.h>
#include <stdint.h>

// Problem constants (from reference setup_inputs):
// B=8 images, N=256*256 pixels/image, P=200 prototypes, C=20 classes.
constexpr int B = 8;
constexpr int N = 256 * 256;
constexpr int P = 200;
constexpr int C = 20;
constexpr int NSLOT = B * C;        // 160 (image,class) accumulator slots
constexpr int MAXNNZ = P * C;       // worst-case nonzeros in identity matrix

// ---------------------------------------------------------------------------
// Kernel 1: zero accumulators + analyze prototype_class_identity [P, C].
// Produces (a) general sparse (idx, weight) lists per class, and (b) a fast
// path descriptor: per-class contiguous run (start, count) valid when the
// class's nonzeros are a contiguous block of 1.0 weights (true for the
// block-diagonal one-hot). ws_flag = 1 iff ALL classes qualify.
// ---------------------------------------------------------------------------
__global__ __launch_bounds__(256) void setup_kernel(
    const float* __restrict__ ident,   // [P, C]
    float* __restrict__ ws_acc,        // 2*NSLOT floats: sums then counts
    int* __restrict__ ws_off,          // [C+1]
    int* __restrict__ ws_idx,          // [MAXNNZ]
    float* __restrict__ ws_w,          // [MAXNNZ]
    int* __restrict__ ws_start,        // [C] fast-path run start
    int* __restrict__ ws_cnt,          // [C] fast-path run length
    int* __restrict__ ws_flag) {       // [1]  1 = fast path usable
  __shared__ int cnts[C];
  __shared__ int soff[C + 1];
  __shared__ int okcls[C];
  const int t = threadIdx.x;

  // zero global accumulators (ws is poisoned 0xAA before every launch)
  for (int i = t; i < 2 * NSLOT; i += blockDim.x) ws_acc[i] = 0.0f;

  if (t < C) {
    int cnt = 0, first = -1, last = -1, uniform = 1;
    for (int p = 0; p < P; ++p) {
      float v = ident[p * C + t];
      if (v != 0.0f) {
        if (first < 0) first = p;
        last = p;
        ++cnt;
        if (v != 1.0f) uniform = 0;
      }
    }
    cnts[t] = cnt;
    const int contig = (cnt == 0) || (last - first + 1 == cnt);
    okcls[t] = (contig && uniform) ? 1 : 0;
    ws_start[t] = (first < 0) ? 0 : first;
    ws_cnt[t] = cnt;
  }
  __syncthreads();
  if (t == 0) {
    int acc = 0, ok = 1;
    for (int c = 0; c < C; ++c) { soff[c] = acc; acc += cnts[c]; ok &= okcls[c]; }
    soff[C] = acc;
    ws_flag[0] = ok;
  }
  __syncthreads();
  if (t <= C) ws_off[t] = soff[t];
  if (t < C) {
    int o = soff[t];
    for (int p = 0; p < P; ++p) {
      float v = ident[p * C + t];
      if (v != 0.0f) { ws_idx[o] = p; ws_w[o] = v; ++o; }
    }
  }
}

// ---------------------------------------------------------------------------
// Kernel 2: the heavy pass. One thread per pixel (grid-stride for safety).
// Fast path: the pixel's class maps to a contiguous weight-1 prototype run
// -> read the 40-B slice with float2 loads (8-B aligned head/tail handled).
// Accumulate into per-block LDS slots, flush once per block via global
// atomics (<= ~40 atomics/block over 320 addresses).
// ---------------------------------------------------------------------------
__global__ __launch_bounds__(256) void main_kernel(
    const float* __restrict__ A,        // [B*N, P]
    const int* __restrict__ labels,     // [B*N]
    const int* __restrict__ ws_off,
    const int* __restrict__ ws_idx,
    const float* __restrict__ ws_w,
    const int* __restrict__ ws_start,
    const int* __restrict__ ws_cnt,
    const int* __restrict__ ws_flag,
    float* __restrict__ ws_acc) {       // sums[NSLOT] then counts[NSLOT]
  __shared__ float s_sum[NSLOT];
  __shared__ float s_cnt[NSLOT];
  __shared__ int s_start[C];
  __shared__ int s_len[C];
  __shared__ int s_off[C + 1];
  __shared__ int s_idx[MAXNNZ];
  __shared__ float s_w[MAXNNZ];

  const int t = threadIdx.x;
  for (int i = t; i < NSLOT; i += blockDim.x) { s_sum[i] = 0.0f; s_cnt[i] = 0.0f; }
  if (t < C) { s_start[t] = ws_start[t]; s_len[t] = ws_cnt[t]; }
  for (int i = t; i <= C; i += blockDim.x) s_off[i] = ws_off[i];
  __syncthreads();
  const int fast = ws_flag[0];          // wave-uniform branch selector
  const int total = s_off[C];
  if (!fast) {
    for (int i = t; i < total; i += blockDim.x) { s_idx[i] = ws_idx[i]; s_w[i] = ws_w[i]; }
  }
  __syncthreads();

  const int NP = B * N;
  const int stride = gridDim.x * blockDim.x;
  for (int i = blockIdx.x * blockDim.x + t; i < NP; i += stride) {
    const int lab = labels[i] - 1;
    if (lab >= 0 && lab < C) {
      const float* row = A + (size_t)i * P;
      float s = 0.0f;
      if (fast) {
        const int p0 = s_start[lab];
        const int cnt = s_len[lab];
        const float* base = row + p0;
        int k = 0;
        // align to 8 B (row base is 16-B aligned; parity of p0 decides)
        if ((p0 & 1) && k < cnt) { s += fabsf(base[k]); ++k; }
        #pragma unroll 5
        for (; k + 1 < cnt; k += 2) {
          const float2 v = *(const float2*)(base + k);
          s += fabsf(v.x) + fabsf(v.y);
        }
        if (k < cnt) s += fabsf(base[k]);
      } else {
        const int o0 = s_off[lab];
        const int o1 = s_off[lab + 1];
        for (int k = o0; k < o1; ++k) s += fabsf(row[s_idx[k]]) * s_w[k];
      }
      const int slot = (i >> 16) * C + lab;   // i / N * C + lab  (N = 2^16)
      atomicAdd(&s_sum[slot], s);
      atomicAdd(&s_cnt[slot], 1.0f);
    }
  }
  __syncthreads();
  for (int i = t; i < NSLOT; i += blockDim.x) {
    const float cv = s_cnt[i];
    if (cv != 0.0f) {
      atomicAdd(&ws_acc[i], s_sum[i]);
      atomicAdd(&ws_acc[NSLOT + i], cv);
    }
  }
}

// ---------------------------------------------------------------------------
// Kernel 3: scalar epilogue. class_norm[b][c] = sum / max(cnt,1) / max(pc,1);
// mean over valid (cnt>0 && proto_count>0) slots.
// ---------------------------------------------------------------------------
__global__ __launch_bounds__(256) void final_kernel(
    const float* __restrict__ ident,
    const float* __restrict__ ws_acc,
    float* __restrict__ out) {
  __shared__ float pc[C];
  __shared__ float red_num[256];
  __shared__ float red_den[256];
  const int t = threadIdx.x;
  if (t < C) {
    float s = 0.0f;
    for (int p = 0; p < P; ++p) s += ident[p * C + t];
    pc[t] = s;
  }
  __syncthreads();
  float num = 0.0f, den = 0.0f;
  for (int i = t; i < NSLOT; i += blockDim.x) {
    const float cnt = ws_acc[NSLOT + i];
    const float p = pc[i % C];
    if (cnt > 0.0f && p > 0.0f) {
      num += ws_acc[i] / fmaxf(cnt, 1.0f) / fmaxf(p, 1.0f);
      den += 1.0f;
    }
  }
  red_num[t] = num;
  red_den[t] = den;
  __syncthreads();
  for (int s = 128; s > 0; s >>= 1) {
    if (t < s) { red_num[t] += red_num[t + s]; red_den[t] += red_den[t + s]; }
    __syncthreads();
  }
  if (t == 0) out[0] = red_num[0] / fmaxf(red_den[0], 1.0f);
}

extern "C" void kernel_launch(void* const* d_in, const int* in_sizes, int n_in,
                              void* d_out, int out_size, void* d_ws, size_t ws_size,
                              hipStream_t stream) {
  const float* A      = (const float*)d_in[0];   // [B, N, P] fp32
  const int*   labels = (const int*)d_in[1];     // [B, H, W] int
  const float* ident  = (const float*)d_in[2];   // [P, C] fp32
  float* out = (float*)d_out;

  // workspace layout (all 4-byte aligned):
  float* ws_acc   = (float*)d_ws;                    // 2*NSLOT floats
  int*   ws_off   = (int*)(ws_acc + 2 * NSLOT);      // C+1 ints
  int*   ws_idx   = ws_off + (C + 1);                // MAXNNZ ints
  float* ws_w     = (float*)(ws_idx + MAXNNZ);       // MAXNNZ floats
  int*   ws_start = (int*)(ws_w + MAXNNZ);           // C ints
  int*   ws_cnt   = ws_start + C;                    // C ints
  int*   ws_flag  = ws_cnt + C;                      // 1 int

  setup_kernel<<<1, 256, 0, stream>>>(ident, ws_acc, ws_off, ws_idx, ws_w,
                                      ws_start, ws_cnt, ws_flag);
  main_kernel<<<2048, 256, 0, stream>>>(A, labels, ws_off, ws_idx, ws_w,
                                        ws_start, ws_cnt, ws_flag, ws_acc);
  final_kernel<<<1, 256, 0, stream>>>(ident, ws_acc, out);
}